// Round 7
// baseline (146.004 us; speedup 1.0000x reference)
//
#include <hip/hip_runtime.h>

#define N_PARTS 62
#define M_SAMP  512
#define D_DIM   256
#define MARGIN  0.2f
#define RSTRIDE 40   // shorts per bf16 tile row (80 B): 20-dword row wheel
                     // {0,20,8,28,16,4,24,12} -> b128 frag reads hit the
                     // 8-dword/bank floor (conflict-free); 16B-aligned.

typedef unsigned short ushort_t;
typedef __attribute__((ext_vector_type(8))) short bf16x8;   // 8 bf16 = 4 VGPRs
typedef __attribute__((ext_vector_type(4))) float f32x4;

__device__ __forceinline__ ushort_t bf16_rne(float f) {
    unsigned u = __float_as_uint(f);
    unsigned r = u + 0x7fffu + ((u >> 16) & 1u);
    return (ushort_t)(r >> 16);
}

__global__ void zero_out_kernel(float* __restrict__ out) {
    if (threadIdx.x < 2 * N_PARTS) out[threadIdx.x] = 0.0f;
}

// R6 post-mortem: staging fp32 in LDS and converting at every USE put 3x
// redundant fp32->bf16 VALU work (B frags converted by all 8 waves; sq pass
// re-converting everything) on the ds_read->MFMA critical path, plus 3M
// cycles of LDS bank conflicts (VALUBusy 47%, MfmaUtil 6.8%, 44 us).
// This revision converts each value EXACTLY ONCE into a double-buffered
// bf16 LDS tile, off the MFMA path (T14 issue-early/write-late):
//   per chunk c: issue 8 fp32 global loads for c+1 (coalesced, to regs)
//   -> frag ds_read_b128 + 16 MFMAs from bf16 tile[c&1]
//   -> convert c+1 (+ sq accumulation of ROUNDED values) -> ds_write_b128
//      into tile[(c+1)&1] -> one barrier.
// 64x64 per-wave tile (acc[4][4]=64 AGPRs); arch-VGPR demand ~85 < the 128
// pin (R1-R3). LDS 88 KB -> 1 block/CU; grid 8x64, XCD-affine (id%8==n%8),
// 248 one-shot blocks.
__global__ __launch_bounds__(512)
__attribute__((amdgpu_waves_per_eu(2, 4)))
void fused_kernel(const float* __restrict__ feat, float* __restrict__ out) {
    const int id = blockIdx.x;
    const int n  = id & 63;          // part
    const int ct = id >> 6;          // col-slab (64 cols, 0..7)
    if (n >= N_PARTS) return;
    const int tid  = threadIdx.x;
    const int wave = tid >> 6, lane = tid & 63;

    __shared__ ushort_t tile[2][512 * RSTRIDE];   // 2 x 40 KB bf16
    __shared__ float sqA[M_SAMP];                 // row sum-of-squares (rounded)
    __shared__ float mrg[8][64][3];               // [wave][col][hp,hn,ds]

    // staging assignment: thread = (row-within-128 rq, 16B k-octet sl)
    const int rq = tid >> 2;      // 0..127
    const int sl = tid & 3;       // k-octet within 32-k chunk
    const float* fb = feat + (size_t)n * (M_SAMP * D_DIM)
                    + (size_t)rq * D_DIM + sl * 8;

    f32x4 acc[4][4] = {};
    float sqp[4] = {0.f, 0.f, 0.f, 0.f};

    // ---- prologue: stage chunk 0 into buf 0
    {
        float4 va[4], vb[4];
        #pragma unroll
        for (int j = 0; j < 4; ++j) {
            const float* p = fb + (size_t)j * 128 * D_DIM;
            va[j] = *(const float4*)(p);
            vb[j] = *(const float4*)(p + 4);
        }
        #pragma unroll
        for (int j = 0; j < 4; ++j) {
            const int row = j * 128 + rq;
            union { bf16x8 v; ushort_t s[8]; } u;
            u.s[0] = bf16_rne(va[j].x); u.s[1] = bf16_rne(va[j].y);
            u.s[2] = bf16_rne(va[j].z); u.s[3] = bf16_rne(va[j].w);
            u.s[4] = bf16_rne(vb[j].x); u.s[5] = bf16_rne(vb[j].y);
            u.s[6] = bf16_rne(vb[j].z); u.s[7] = bf16_rne(vb[j].w);
            float s = 0.f;
            #pragma unroll
            for (int e = 0; e < 8; ++e) {
                const float r = __uint_as_float((unsigned)u.s[e] << 16);
                s += r * r;
            }
            sqp[j] += s;
            *(bf16x8*)&tile[0][row * RSTRIDE + sl * 8] = u.v;
        }
    }
    __syncthreads();

    // ---- fragment addressing (A row / B row = slab col; k-octet = lane>>4)
    const int fr = lane & 15, q = lane >> 4;
    const int abase = (wave * 64 + fr) * RSTRIDE + q * 8;
    const int bbase = (ct * 64 + fr) * RSTRIDE + q * 8;

    #pragma unroll
    for (int c = 0; c < 8; ++c) {
        // issue next-chunk global loads first (latency hides under MFMA)
        float4 va[4], vb[4];
        if (c < 7) {
            #pragma unroll
            for (int j = 0; j < 4; ++j) {
                const float* p = fb + (size_t)j * 128 * D_DIM + (c + 1) * 32;
                va[j] = *(const float4*)(p);
                vb[j] = *(const float4*)(p + 4);
            }
        }
        const ushort_t* tb = tile[c & 1];
        bf16x8 af[4];
        #pragma unroll
        for (int mi = 0; mi < 4; ++mi)
            af[mi] = *(const bf16x8*)&tb[abase + mi * 16 * RSTRIDE];
        #pragma unroll
        for (int ni = 0; ni < 4; ++ni) {
            const bf16x8 bfv = *(const bf16x8*)&tb[bbase + ni * 16 * RSTRIDE];
            #pragma unroll
            for (int mi = 0; mi < 4; ++mi)
                acc[mi][ni] = __builtin_amdgcn_mfma_f32_16x16x32_bf16(
                    af[mi], bfv, acc[mi][ni], 0, 0, 0);
        }
        // convert + write chunk c+1 into the other buffer (write-late)
        if (c < 7) {
            ushort_t* tn = tile[(c + 1) & 1];
            #pragma unroll
            for (int j = 0; j < 4; ++j) {
                const int row = j * 128 + rq;
                union { bf16x8 v; ushort_t s[8]; } u;
                u.s[0] = bf16_rne(va[j].x); u.s[1] = bf16_rne(va[j].y);
                u.s[2] = bf16_rne(va[j].z); u.s[3] = bf16_rne(va[j].w);
                u.s[4] = bf16_rne(vb[j].x); u.s[5] = bf16_rne(vb[j].y);
                u.s[6] = bf16_rne(vb[j].z); u.s[7] = bf16_rne(vb[j].w);
                float s = 0.f;
                #pragma unroll
                for (int e = 0; e < 8; ++e) {
                    const float r = __uint_as_float((unsigned)u.s[e] << 16);
                    s += r * r;
                }
                sqp[j] += s;
                *(bf16x8*)&tn[row * RSTRIDE + sl * 8] = u.v;
            }
        }
        __syncthreads();
    }

    // ---- finalize row sum-of-squares: reduce 4 sl-partials per row
    #pragma unroll
    for (int j = 0; j < 4; ++j) {
        float s = sqp[j];
        s += __shfl_xor(s, 1);
        s += __shfl_xor(s, 2);
        if (sl == 0) sqA[j * 128 + wave * 16 + (lane >> 2)] = s;
    }
    __syncthreads();

    // ---- epilogue (verified structure; SQ from LDS). C/D layout:
    // col = lane&15, row = (lane>>4)*4 + reg.
    float sqr[4][4];
    #pragma unroll
    for (int mi = 0; mi < 4; ++mi)
        #pragma unroll
        for (int p = 0; p < 4; ++p)
            sqr[mi][p] = sqA[wave * 64 + mi * 16 + (lane >> 4) * 4 + p];

    #pragma unroll
    for (int ni = 0; ni < 4; ++ni) {
        const int C = ct * 64 + ni * 16 + (lane & 15);     // part-local col
        const float sc = sqA[C];
        const int Cg = C >> 3;                             // label = m>>3
        float ds = 0.f, hp = 0.f, hn = 1e30f;
        #pragma unroll
        for (int mi = 0; mi < 4; ++mi) {
            #pragma unroll
            for (int p = 0; p < 4; ++p) {
                const int R = wave * 64 + mi * 16 + (lane >> 4) * 4 + p;
                const float d2 = sqr[mi][p] + sc - 2.f * acc[mi][ni][p];
                const float d  = __builtin_amdgcn_sqrtf(fmaxf(d2, 0.f));
                ds += d;
                if ((R >> 3) == Cg) hp = fmaxf(hp, d);
                else                hn = fminf(hn, d);
            }
        }
        // combine the 4 quads (same col, disjoint row subsets)
        #pragma unroll
        for (int off = 16; off < 64; off <<= 1) {
            ds += __shfl_xor(ds, off);
            hp = fmaxf(hp, __shfl_xor(hp, off));
            hn = fminf(hn, __shfl_xor(hn, off));
        }
        if (lane < 16) {
            mrg[wave][ni * 16 + lane][0] = hp;
            mrg[wave][ni * 16 + lane][1] = hn;
            mrg[wave][ni * 16 + lane][2] = ds;
        }
    }
    __syncthreads();
    if (tid < 64) {   // col tid of the slab: merge 8 row-strips, then reduce
        float hp = 0.f, hn = 1e30f, bd = 0.f;
        #pragma unroll
        for (int w = 0; w < 8; ++w) {
            hp = fmaxf(hp, mrg[w][tid][0]);
            hn = fminf(hn, mrg[w][tid][1]);
            bd += mrg[w][tid][2];
        }
        float bl = fmaxf(MARGIN + hp - hn, 0.f);
        #pragma unroll
        for (int off = 32; off > 0; off >>= 1) {
            bl += __shfl_xor(bl, off);
            bd += __shfl_xor(bd, off);
        }
        if (tid == 0) {
            atomicAdd(&out[n],           bl * (1.0f / 512.0f));
            atomicAdd(&out[N_PARTS + n], bd * (1.0f / (512.0f * 512.0f)));
        }
    }
}

extern "C" void kernel_launch(void* const* d_in, const int* in_sizes, int n_in,
                              void* d_out, int out_size, void* d_ws, size_t ws_size,
                              hipStream_t stream) {
    const float* feat = (const float*)d_in[0];    // [62, 512, 256] fp32
    float* out = (float*)d_out;                   // [124]
    (void)d_ws; (void)ws_size;                    // no workspace needed

    zero_out_kernel<<<dim3(1), 128, 0, stream>>>(out);
    fused_kernel<<<dim3(8 * 64), 512, 0, stream>>>(feat, out);
}

// Round 8
// 100.458 us; speedup vs baseline: 1.4534x; 1.4534x over previous
//
#include <hip/hip_runtime.h>

#define N_PARTS 62
#define M_SAMP  512
#define D_DIM   256
#define MARGIN  0.2f
#define RSTRIDE 40   // shorts per bf16 tile row = 5 x 16B slots. Start slot of
                     // (row,q) = 5*row + q: within any 8-consecutive-lane
                     // group this covers all 8 bank-classes once -> b128
                     // reads/writes conflict-free (8-lane-group model, R7 PM).

typedef unsigned short ushort_t;
typedef __attribute__((ext_vector_type(8))) short bf16x8;   // 8 bf16 = 4 VGPRs
typedef __attribute__((ext_vector_type(4))) float f32x4;

typedef const __attribute__((address_space(1))) unsigned gu32;
typedef __attribute__((address_space(3))) unsigned lu32;

__device__ __forceinline__ ushort_t bf16_rne(float f) {
    unsigned u = __float_as_uint(f);
    unsigned r = u + 0x7fffu + ((u >> 16) & 1u);
    return (ushort_t)(r >> 16);
}

__global__ void zero_out_kernel(float* __restrict__ out) {
    if (threadIdx.x < 2 * N_PARTS) out[threadIdx.x] = 0.0f;
}

// R7 post-mortem: reg-staging re-triggered the 128-VGPR spill (WRITE 55MB,
// 86us). R6 (global_load_lds) was spill-free but paid 3x redundant cvt on
// the MFMA path + b128 phase conflicts. This version:
//  - global_load_lds fp32 -> single 64KB LDS buffer, XOR-swizzled GLOBAL
//    source (R6-verified): zero staging VGPRs; c+1 loads fly under c MFMAs.
//  - dedicated conversion phase per chunk (between barriers): thread t
//    converts row t once (8x b128 fp32 reads at slots i^(t&7): group-
//    conflict-free) -> bf16 tile (stride-40, group-conflict-free) and
//    accumulates row t's sum-of-squares in one scalar (no shuffles).
//  - MFMA phase is a pure ds_read_b128 -> mfma stream on the bf16 tile.
// VGPR demand ~115 < the 128 pin. LDS 152KB -> 1 block/CU. Grid 8x64,
// XCD-affine (id%8==n%8).
__global__ __launch_bounds__(512)
__attribute__((amdgpu_waves_per_eu(2, 4)))
void fused_kernel(const float* __restrict__ feat, float* __restrict__ out) {
    const int id = blockIdx.x;
    const int n  = id & 63;          // part
    const int ct = id >> 6;          // col-slab (64 cols, 0..7)
    if (n >= N_PARTS) return;
    const int tid  = threadIdx.x;
    const int wave = tid >> 6, lane = tid & 63;

    __shared__ float    f32buf[512 * 32];          // 64 KB, slot-swizzled
    __shared__ ushort_t bt[2][512 * RSTRIDE];      // 2 x 40 KB bf16
    __shared__ float    sqA[M_SAMP];               // row sum-of-squares
    __shared__ float    mrg[8][64][3];             // [wave][col][hp,hn,ds]

    const float* fpart = feat + (size_t)n * (M_SAMP * D_DIM);

    // Staging (R6-verified): issue s covers rows s*8..s*8+7. Lane l -> row
    // s*8+(l>>3), LDS 16B-slot l&7; global source pre-swizzled so
    // f32buf[row][slot j] = global float4 j^(row&7).
    const int srow = lane >> 3;
    const int scol = (lane & 7) ^ srow;
    const float* gbase = fpart + (size_t)srow * D_DIM + (size_t)scol * 4;

    // ---- prologue: stage chunk 0
    #pragma unroll
    for (int j = 0; j < 8; ++j) {
        const int s = wave + 8 * j;
        __builtin_amdgcn_global_load_lds(
            (gu32*)(gbase + (size_t)s * 8 * D_DIM),
            (lu32*)(uintptr_t)&f32buf[s * 256], 16, 0, 0);
    }
    __syncthreads();

    const int sx = tid & 7;          // swizzle key of row tid
    float sqp = 0.f;

    // conversion phase: thread t -> row t (32 floats), once per chunk
#define CONVERT_CHUNK(DST)                                                   \
    {                                                                        \
        ushort_t* dp = (DST) + tid * RSTRIDE;                                \
        _Pragma("unroll")                                                    \
        for (int i = 0; i < 8; i += 2) {                                     \
            const f32x4 v0 = *(const f32x4*)&f32buf[tid * 32 + ((i ^ sx) << 2)];       \
            const f32x4 v1 = *(const f32x4*)&f32buf[tid * 32 + (((i + 1) ^ sx) << 2)]; \
            union { bf16x8 v; ushort_t s[8]; } u;                            \
            u.s[0] = bf16_rne(v0.x); u.s[1] = bf16_rne(v0.y);                \
            u.s[2] = bf16_rne(v0.z); u.s[3] = bf16_rne(v0.w);                \
            u.s[4] = bf16_rne(v1.x); u.s[5] = bf16_rne(v1.y);                \
            u.s[6] = bf16_rne(v1.z); u.s[7] = bf16_rne(v1.w);                \
            _Pragma("unroll")                                                \
            for (int e = 0; e < 8; ++e) {                                    \
                const float r = __uint_as_float((unsigned)u.s[e] << 16);     \
                sqp += r * r;                                                \
            }                                                                \
            *(bf16x8*)&dp[(i >> 1) * 8] = u.v;                               \
        }                                                                    \
    }

    // convert chunk 0 into bt[0]
    CONVERT_CHUNK(bt[0]);
    __syncthreads();

    // fragment addressing: lane = (fr = row-in-group, q = k-octet)
    const int fr = lane & 15, q = lane >> 4;
    const int abase = (wave * 64 + fr) * RSTRIDE + q * 8;
    const int bbase = (ct * 64 + fr) * RSTRIDE + q * 8;

    f32x4 acc[4][4] = {};

    #pragma unroll
    for (int c = 0; c < 8; ++c) {
        // issue next-chunk staging (overlaps this chunk's MFMAs)
        if (c < 7) {
            #pragma unroll
            for (int j = 0; j < 8; ++j) {
                const int s = wave + 8 * j;
                __builtin_amdgcn_global_load_lds(
                    (gu32*)(gbase + (size_t)s * 8 * D_DIM + (c + 1) * 32),
                    (lu32*)(uintptr_t)&f32buf[s * 256], 16, 0, 0);
            }
        }
        // MFMA phase: pure ds_read_b128 -> mfma
        const ushort_t* tb = bt[c & 1];
        bf16x8 af[4];
        #pragma unroll
        for (int mi = 0; mi < 4; ++mi)
            af[mi] = *(const bf16x8*)&tb[abase + mi * 16 * RSTRIDE];
        #pragma unroll
        for (int ni = 0; ni < 4; ++ni) {
            const bf16x8 bfv = *(const bf16x8*)&tb[bbase + ni * 16 * RSTRIDE];
            #pragma unroll
            for (int mi = 0; mi < 4; ++mi)
                acc[mi][ni] = __builtin_amdgcn_mfma_f32_16x16x32_bf16(
                    af[mi], bfv, acc[mi][ni], 0, 0, 0);
        }
        __syncthreads();   // drains vmcnt: chunk c+1 fp32 arrived; all bt reads done
        if (c < 7) {
            CONVERT_CHUNK(bt[(c + 1) & 1]);
            __syncthreads();   // bf16 writes visible; f32buf free for next issue
        }
    }

    sqA[tid] = sqp;
    __syncthreads();

    // ---- epilogue (verified structure). C/D layout: col = lane&15,
    // row = (lane>>4)*4 + reg.
    float sqr[4][4];
    #pragma unroll
    for (int mi = 0; mi < 4; ++mi)
        #pragma unroll
        for (int p = 0; p < 4; ++p)
            sqr[mi][p] = sqA[wave * 64 + mi * 16 + (lane >> 4) * 4 + p];

    #pragma unroll
    for (int ni = 0; ni < 4; ++ni) {
        const int C = ct * 64 + ni * 16 + (lane & 15);     // part-local col
        const float sc = sqA[C];
        const int Cg = C >> 3;                             // label = m>>3
        float ds = 0.f, hp = 0.f, hn = 1e30f;
        #pragma unroll
        for (int mi = 0; mi < 4; ++mi) {
            #pragma unroll
            for (int p = 0; p < 4; ++p) {
                const int R = wave * 64 + mi * 16 + (lane >> 4) * 4 + p;
                const float d2 = sqr[mi][p] + sc - 2.f * acc[mi][ni][p];
                const float d  = __builtin_amdgcn_sqrtf(fmaxf(d2, 0.f));
                ds += d;
                if ((R >> 3) == Cg) hp = fmaxf(hp, d);
                else                hn = fminf(hn, d);
            }
        }
        // combine the 4 quads (same col, disjoint row subsets)
        #pragma unroll
        for (int off = 16; off < 64; off <<= 1) {
            ds += __shfl_xor(ds, off);
            hp = fmaxf(hp, __shfl_xor(hp, off));
            hn = fminf(hn, __shfl_xor(hn, off));
        }
        if (lane < 16) {
            mrg[wave][ni * 16 + lane][0] = hp;
            mrg[wave][ni * 16 + lane][1] = hn;
            mrg[wave][ni * 16 + lane][2] = ds;
        }
    }
    __syncthreads();
    if (tid < 64) {   // col tid of the slab: merge 8 row-strips, then reduce
        float hp = 0.f, hn = 1e30f, bd = 0.f;
        #pragma unroll
        for (int w = 0; w < 8; ++w) {
            hp = fmaxf(hp, mrg[w][tid][0]);
            hn = fminf(hn, mrg[w][tid][1]);
            bd += mrg[w][tid][2];
        }
        float bl = fmaxf(MARGIN + hp - hn, 0.f);
        #pragma unroll
        for (int off = 32; off > 0; off >>= 1) {
            bl += __shfl_xor(bl, off);
            bd += __shfl_xor(bd, off);
        }
        if (tid == 0) {
            atomicAdd(&out[n],           bl * (1.0f / 512.0f));
            atomicAdd(&out[N_PARTS + n], bd * (1.0f / (512.0f * 512.0f)));
        }
    }
}

extern "C" void kernel_launch(void* const* d_in, const int* in_sizes, int n_in,
                              void* d_out, int out_size, void* d_ws, size_t ws_size,
                              hipStream_t stream) {
    const float* feat = (const float*)d_in[0];    // [62, 512, 256] fp32
    float* out = (float*)d_out;                   // [124]
    (void)d_ws; (void)ws_size;                    // no workspace needed

    zero_out_kernel<<<dim3(1), 128, 0, stream>>>(out);
    fused_kernel<<<dim3(8 * 64), 512, 0, stream>>>(feat, out);
}